// Round 1
// baseline (7685.226 us; speedup 1.0000x reference)
//
#include <hip/hip_runtime.h>
#include <hip/hip_bf16.h>

// Problem constants
// B=64, S=512, T=64, E=H=512, V=128, G=4H=2048, Kgates=512(ctx)+512(h)+128(tgt)=1152

#define DI __device__ __forceinline__
typedef __hip_bfloat16 bf16;
typedef __hip_bfloat162 bf162;

DI float2 bf2f2(unsigned int u) {
  bf162 b = *reinterpret_cast<const bf162*>(&u);
  return __bfloat1622float2(b);
}
DI float sigm(float x) { return 1.f / (1.f + expf(-x)); }

// ---------------------------------------------------------------------------
// Generic 64x64-tile fp32 GEMM: C[m,n] = sum_k A[m,k] * B'[k,n] (+bias[n])
// BT=false: B is (K x N) row-major.  BT=true: B is (N x K) row-major (A·Bt).
// OBF: store C as bf16.
// ---------------------------------------------------------------------------
template<bool BT, bool OBF>
__launch_bounds__(256)
__global__ void gemm64(const float* __restrict__ A, const float* __restrict__ Bm,
                       void* __restrict__ Cp, const float* __restrict__ bias,
                       int M, int N, int K, int lda, int ldb, int ldc) {
  __shared__ __align__(16) float As[16][68];
  __shared__ __align__(16) float Bs[16][68];
  const int tid = threadIdx.x;
  const int n0 = blockIdx.x * 64;
  const int m0 = blockIdx.y * 64;
  const int tx = tid & 15, ty = tid >> 4;
  const int arow = tid >> 2;          // 0..63
  const int acol = (tid & 3) * 4;     // 0,4,8,12
  float acc[4][4] = {};
  for (int k0 = 0; k0 < K; k0 += 16) {
    float4 a4 = *(const float4*)&A[(size_t)(m0 + arow) * lda + k0 + acol];
    As[acol + 0][arow] = a4.x; As[acol + 1][arow] = a4.y;
    As[acol + 2][arow] = a4.z; As[acol + 3][arow] = a4.w;
    if (BT) {
      float4 b4 = *(const float4*)&Bm[(size_t)(n0 + arow) * ldb + k0 + acol];
      Bs[acol + 0][arow] = b4.x; Bs[acol + 1][arow] = b4.y;
      Bs[acol + 2][arow] = b4.z; Bs[acol + 3][arow] = b4.w;
    } else {
      const int brow = tid >> 4;          // 0..15
      const int bcol = (tid & 15) * 4;    // 0..60
      float4 b4 = *(const float4*)&Bm[(size_t)(k0 + brow) * ldb + n0 + bcol];
      *(float4*)&Bs[brow][bcol] = b4;
    }
    __syncthreads();
#pragma unroll
    for (int kk = 0; kk < 16; kk++) {
      float4 av = *(const float4*)&As[kk][ty * 4];
      float4 bv = *(const float4*)&Bs[kk][tx * 4];
      float a_[4] = {av.x, av.y, av.z, av.w};
      float b_[4] = {bv.x, bv.y, bv.z, bv.w};
#pragma unroll
      for (int i = 0; i < 4; i++)
#pragma unroll
        for (int j = 0; j < 4; j++) acc[i][j] += a_[i] * b_[j];
    }
    __syncthreads();
  }
#pragma unroll
  for (int i = 0; i < 4; i++) {
    const int m = m0 + ty * 4 + i;
#pragma unroll
    for (int j = 0; j < 4; j++) {
      const int n = n0 + tx * 4 + j;
      float v = acc[i][j] + (bias ? bias[n] : 0.f);
      if (OBF) ((bf16*)Cp)[(size_t)m * ldc + n] = __float2bfloat16(v);
      else     ((float*)Cp)[(size_t)m * ldc + n] = v;
    }
  }
}

// ---------------------------------------------------------------------------
// Small precompute kernels
// ---------------------------------------------------------------------------
__launch_bounds__(256)
__global__ void transpose512(const float* __restrict__ src, float* __restrict__ dst) {
  int idx = blockIdx.x * 256 + threadIdx.x;   // 512*512
  int r = idx >> 9, c = idx & 511;
  dst[(size_t)c * 512 + r] = src[idx];        // dst[m][f] = src[f][m]
}

// outv[e] = sum_f bvec[f] * W[f*512 + e]   (column-weighted sum; coalesced)
__launch_bounds__(256)
__global__ void colvec_kernel(const float* __restrict__ bvec, const float* __restrict__ W,
                              float* __restrict__ outv) {
  int e = blockIdx.x * 256 + threadIdx.x;
  float acc = 0.f;
  for (int f = 0; f < 512; f++) acc += bvec[f] * W[(size_t)f * 512 + e];
  outv[e] = acc;
}

__launch_bounds__(256)
__global__ void dot_kernel(const float* __restrict__ a, const float* __restrict__ b,
                           float* __restrict__ outp) {
  __shared__ float red[256];
  int tid = threadIdx.x;
  red[tid] = a[tid] * b[tid] + a[tid + 256] * b[tid + 256];
  __syncthreads();
  for (int st = 128; st > 0; st >>= 1) {
    if (tid < st) red[tid] += red[tid + st];
    __syncthreads();
  }
  if (tid == 0) *outp = red[0];
}

// svec[bs] = memory[bs,:]·wb + dotc    (bq·K term of the scores)
__launch_bounds__(256)
__global__ void svec_kernel(const float* __restrict__ mem, const float* __restrict__ wb,
                            const float* __restrict__ dotc, float* __restrict__ svec) {
  __shared__ __align__(16) float ws_[512];
  int tid = threadIdx.x;
  *(float2*)&ws_[tid * 2] = *(const float2*)&wb[tid * 2];
  __syncthreads();
  int bs = blockIdx.x * 256 + tid;
  const float4* mr = (const float4*)&mem[(size_t)bs * 512];
  const float4* w4 = (const float4*)ws_;
  float acc = *dotc;
#pragma unroll 4
  for (int j = 0; j < 128; j++) {
    float4 m = mr[j], w = w4[j];
    acc += m.x * w.x + m.y * w.y + m.z * w.z + m.w * w.w;
  }
  svec[bs] = acc;
}

// bias_g[j] = b_ih[j] + b_hh[j] + sum_f bo[f]*W_ih[j,f]   (Wo-bias folded in)
__launch_bounds__(256)
__global__ void biasg_kernel(const float* __restrict__ W_ih, const float* __restrict__ b_ih,
                             const float* __restrict__ b_hh, const float* __restrict__ bo,
                             float* __restrict__ biasg) {
  int j = blockIdx.x * 256 + threadIdx.x;   // 0..2047
  float acc = b_ih[j] + b_hh[j];
  const float4* wr = (const float4*)&W_ih[(size_t)j * 640];
  const float4* br = (const float4*)bo;
#pragma unroll 4
  for (int f4 = 0; f4 < 128; f4++) {
    float4 w = wr[f4], bb = br[f4];
    acc += w.x * bb.x + w.y * bb.y + w.z * bb.z + w.w * bb.w;
  }
  biasg[j] = acc;
}

// Wcomb[:,512:1024] = W_hh ; Wcomb[:,1024:1152] = W_ih[:,512:640]
__launch_bounds__(256)
__global__ void wcomb_copy(const float* __restrict__ W_hh, const float* __restrict__ W_ih,
                           float* __restrict__ Wcomb) {
  int idx = blockIdx.x * 256 + threadIdx.x;   // < 2048*640
  int j = idx / 640, cc = idx % 640;
  float v = (cc < 512) ? W_hh[(size_t)j * 512 + cc] : W_ih[(size_t)j * 640 + cc];
  Wcomb[(size_t)j * 1152 + 512 + cc] = v;
}

// ---------------------------------------------------------------------------
// Per-step kernels
// ---------------------------------------------------------------------------
// One block per batch element: cls(t-1) + scores(h·K2+svec)*scale + softmax + ctx
__launch_bounds__(256)
__global__ void attn_kernel(const bf16* __restrict__ K2, const bf16* __restrict__ Vv,
                            const float* __restrict__ svec, const float* __restrict__ h,
                            const float* __restrict__ Wcls, const float* __restrict__ bcls,
                            float* __restrict__ ctx, float* __restrict__ out, int t) {
  __shared__ __align__(16) float hs[512];
  __shared__ __align__(16) float sc[512];
  __shared__ float red[256];
  const int b = blockIdx.x, tid = threadIdx.x;
  *(float2*)&hs[tid * 2] = *(const float2*)&h[(size_t)b * 512 + tid * 2];
  __syncthreads();

  // classifier for the previous step's h (teacher-forced outputs)
  if (t > 0 && tid < 128) {
    float acc = 0.f;
    const float4* wr = (const float4*)&Wcls[(size_t)tid * 512];
    const float4* hr = (const float4*)hs;
#pragma unroll 4
    for (int j = 0; j < 128; j++) {
      float4 w = wr[j], hh = hr[j];
      acc += w.x * hh.x + w.y * hh.y + w.z * hh.z + w.w * hh.w;
    }
    out[((size_t)b * 64 + (t - 1)) * 128 + tid] = acc + bcls[tid];
  }

  // scores: 2 rows per thread, K2 row dot h
  const float SCALE = 0.04419417382415922f;  // 1/sqrt(512)
  const float4* h4 = (const float4*)hs;
#pragma unroll
  for (int si = 0; si < 2; si++) {
    const int s = tid + si * 256;
    const uint4* kr = (const uint4*)&K2[((size_t)b * 512 + s) * 512];
    float acc = 0.f;
#pragma unroll 4
    for (int j = 0; j < 64; j++) {
      uint4 q = kr[j];
      float4 ha = h4[2 * j], hb = h4[2 * j + 1];
      float2 p0 = bf2f2(q.x), p1 = bf2f2(q.y), p2 = bf2f2(q.z), p3 = bf2f2(q.w);
      acc += p0.x * ha.x + p0.y * ha.y + p1.x * ha.z + p1.y * ha.w
           + p2.x * hb.x + p2.y * hb.y + p3.x * hb.z + p3.y * hb.w;
    }
    sc[s] = (acc + svec[(size_t)b * 512 + s]) * SCALE;
  }
  __syncthreads();

  // softmax over 512 (max, exp, sum; normalize at ctx store)
  red[tid] = fmaxf(sc[tid], sc[tid + 256]);
  __syncthreads();
  for (int st = 128; st > 0; st >>= 1) {
    if (tid < st) red[tid] = fmaxf(red[tid], red[tid + st]);
    __syncthreads();
  }
  const float mx = red[0];
  __syncthreads();
  float e0 = expf(sc[tid] - mx), e1 = expf(sc[tid + 256] - mx);
  sc[tid] = e0; sc[tid + 256] = e1;
  red[tid] = e0 + e1;
  __syncthreads();
  for (int st = 128; st > 0; st >>= 1) {
    if (tid < st) red[tid] += red[tid + st];
    __syncthreads();
  }
  const float inv = 1.0f / red[0];

  // ctx[b,e] = sum_s attn[s] * V[b,s,e]; coalesced bf162 loads
  const int e = tid * 2;
  float cx = 0.f, cy = 0.f;
  const bf16* vbase = &Vv[(size_t)b * 512 * 512 + e];
#pragma unroll 4
  for (int s = 0; s < 512; s++) {
    float w = sc[s];
    float2 vv = __bfloat1622float2(*(const bf162*)&vbase[(size_t)s * 512]);
    cx += w * vv.x; cy += w * vv.y;
  }
  ctx[(size_t)b * 512 + e]     = cx * inv;
  ctx[(size_t)b * 512 + e + 1] = cy * inv;
}

// gates partial GEMM: gpart[ks][b][j] = sum_{k in split} X[b,k]*Wcomb[j,k]
// X = [ctx | h | tgt[:,t,:]], K=1152 split in 2; grid (128 n-tiles of 16, 2)
__launch_bounds__(256)
__global__ void gates_kernel(const float* __restrict__ ctx, const float* __restrict__ h,
                             const float* __restrict__ tgt, const float* __restrict__ Wcomb,
                             float* __restrict__ gpart, int t) {
  __shared__ __align__(16) float As[16][68];
  __shared__ float Bs[16][17];
  const int tid = threadIdx.x;
  const int n0 = blockIdx.x * 16;
  const int ks = blockIdx.y;
  const int tx = tid & 15, ty = tid >> 4;
  const int arow = tid >> 2, acol0 = (tid & 3) * 4;
  float acc[4] = {0.f, 0.f, 0.f, 0.f};
  for (int k0 = ks * 576; k0 < ks * 576 + 576; k0 += 16) {
#pragma unroll
    for (int j = 0; j < 4; j++) {
      const int k = k0 + acol0 + j;
      float v;
      if (k < 512)       v = ctx[(size_t)arow * 512 + k];
      else if (k < 1024) v = h[(size_t)arow * 512 + (k - 512)];
      else               v = tgt[((size_t)arow * 64 + t) * 128 + (k - 1024)];
      As[acol0 + j][arow] = v;
    }
    Bs[tx][ty] = Wcomb[(size_t)(n0 + ty) * 1152 + k0 + tx];
    __syncthreads();
#pragma unroll
    for (int kk = 0; kk < 16; kk++) {
      const float bv = Bs[kk][tx];
      float4 av = *(const float4*)&As[kk][ty * 4];
      acc[0] += av.x * bv; acc[1] += av.y * bv;
      acc[2] += av.z * bv; acc[3] += av.w * bv;
    }
    __syncthreads();
  }
#pragma unroll
  for (int i = 0; i < 4; i++) {
    const int m = ty * 4 + i;
    gpart[(size_t)ks * 131072 + (size_t)m * 2048 + n0 + tx] = acc[i];
  }
}

// cell update: combine split-K partials + bias, LSTM gate math, write h,c
__launch_bounds__(256)
__global__ void cell_kernel(const float* __restrict__ gpart, const float* __restrict__ biasg,
                            float* __restrict__ h, float* __restrict__ c) {
  const int idx = blockIdx.x * 256 + threadIdx.x;   // 0..32767
  const int b = idx >> 9, d = idx & 511;
  const float* g0 = gpart + (size_t)b * 2048;
  const float* g1 = gpart + 131072 + (size_t)b * 2048;
  float gi = g0[d] + g1[d] + biasg[d];
  float gf = g0[512 + d] + g1[512 + d] + biasg[512 + d];
  float gg = g0[1024 + d] + g1[1024 + d] + biasg[1024 + d];
  float go = g0[1536 + d] + g1[1536 + d] + biasg[1536 + d];
  float cn = sigm(gf) * c[idx] + sigm(gi) * tanhf(gg);
  float hn = sigm(go) * tanhf(cn);
  c[idx] = cn; h[idx] = hn;
}

// final classifier (t = T-1)
__launch_bounds__(256)
__global__ void cls_kernel(const float* __restrict__ h, const float* __restrict__ Wcls,
                           const float* __restrict__ bcls, float* __restrict__ out) {
  __shared__ __align__(16) float hs[512];
  const int b = blockIdx.x, tid = threadIdx.x;
  *(float2*)&hs[tid * 2] = *(const float2*)&h[(size_t)b * 512 + tid * 2];
  __syncthreads();
  if (tid < 128) {
    float acc = 0.f;
    const float4* wr = (const float4*)&Wcls[(size_t)tid * 512];
    const float4* hr = (const float4*)hs;
#pragma unroll 4
    for (int j = 0; j < 128; j++) {
      float4 w = wr[j], hh = hr[j];
      acc += w.x * hh.x + w.y * hh.y + w.z * hh.z + w.w * hh.w;
    }
    out[((size_t)b * 64 + 63) * 128 + tid] = acc + bcls[tid];
  }
}

// ---------------------------------------------------------------------------
extern "C" void kernel_launch(void* const* d_in, const int* in_sizes, int n_in,
                              void* d_out, int out_size, void* d_ws, size_t ws_size,
                              hipStream_t stream) {
  const float* memory = (const float*)d_in[0];
  const float* tgt    = (const float*)d_in[1];
  const float* Wq     = (const float*)d_in[2];
  const float* bq     = (const float*)d_in[3];
  const float* Wk     = (const float*)d_in[4];
  const float* bk     = (const float*)d_in[5];
  const float* Wv     = (const float*)d_in[6];
  const float* bv     = (const float*)d_in[7];
  const float* Wo     = (const float*)d_in[8];
  const float* bo     = (const float*)d_in[9];
  const float* W_ih   = (const float*)d_in[10];
  const float* b_ih   = (const float*)d_in[11];
  const float* W_hh   = (const float*)d_in[12];
  const float* b_hh   = (const float*)d_in[13];
  const float* Wcls   = (const float*)d_in[14];
  const float* bcls   = (const float*)d_in[15];
  float* out = (float*)d_out;

  float* ws = (float*)d_ws;
  size_t off = 0;
  auto alloc = [&](size_t n) { size_t r = off; off += (n + 15) & ~(size_t)15; return r; };
  const size_t K2_off    = alloc(8388608);   // bf16 x 16777216 (B,S,E)
  const size_t V_off     = alloc(8388608);   // bf16 x 16777216
  const size_t Wcomb_off = alloc(2359296);   // 2048 x 1152
  const size_t Wkq_off   = alloc(262144);
  const size_t WkT_off   = alloc(262144);
  const size_t svec_off  = alloc(32768);
  const size_t sb_off    = alloc(512);
  const size_t wb_off    = alloc(512);
  const size_t dotc_off  = alloc(16);
  const size_t biasg_off = alloc(2048);
  const size_t h_off     = alloc(32768);
  const size_t c_off     = alloc(32768);     // contiguous with h (single memset)
  const size_t ctx_off   = alloc(32768);
  const size_t gpart_off = alloc(262144);    // 2 x 64 x 2048

  bf16* K2 = (bf16*)(ws + K2_off);
  bf16* Vv = (bf16*)(ws + V_off);

  // zero h and c (adjacent)
  hipMemsetAsync(ws + h_off, 0, 2 * 32768 * sizeof(float), stream);

  // ---- precompute (step-invariant) ----
  transpose512<<<1024, 256, 0, stream>>>(Wk, ws + WkT_off);
  colvec_kernel<<<2, 256, 0, stream>>>(bk, Wq, ws + sb_off);   // sb[e]=sum_f bk[f]Wq[f,e]
  colvec_kernel<<<2, 256, 0, stream>>>(bq, Wk, ws + wb_off);   // wb[m]=sum_f bq[f]Wk[f,m]
  dot_kernel<<<1, 256, 0, stream>>>(bq, bk, ws + dotc_off);
  // Wkq = WkT @ Wq
  gemm64<false, false><<<dim3(8, 8), 256, 0, stream>>>(
      ws + WkT_off, Wq, ws + Wkq_off, nullptr, 512, 512, 512, 512, 512, 512);
  // K2 = memory @ Wkq + sb  (bf16 out)
  gemm64<false, true><<<dim3(8, 512), 256, 0, stream>>>(
      memory, ws + Wkq_off, K2, ws + sb_off, 32768, 512, 512, 512, 512, 512);
  // V = memory @ Wv^T + bv  (bf16 out)
  gemm64<true, true><<<dim3(8, 512), 256, 0, stream>>>(
      memory, Wv, Vv, bv, 32768, 512, 512, 512, 512, 512);
  // Wcomb[:, :512] = W_ih[:, :512] @ Wo
  gemm64<false, false><<<dim3(8, 32), 256, 0, stream>>>(
      W_ih, Wo, ws + Wcomb_off, nullptr, 2048, 512, 512, 640, 512, 1152);
  wcomb_copy<<<5120, 256, 0, stream>>>(W_hh, W_ih, ws + Wcomb_off);
  biasg_kernel<<<8, 256, 0, stream>>>(W_ih, b_ih, b_hh, bo, ws + biasg_off);
  svec_kernel<<<128, 256, 0, stream>>>(memory, ws + wb_off, ws + dotc_off, ws + svec_off);

  // ---- recurrent loop ----
  for (int t = 0; t < 64; t++) {
    attn_kernel<<<64, 256, 0, stream>>>(K2, Vv, ws + svec_off, ws + h_off,
                                        Wcls, bcls, ws + ctx_off, out, t);
    gates_kernel<<<dim3(128, 2), 256, 0, stream>>>(ws + ctx_off, ws + h_off, tgt,
                                                   ws + Wcomb_off, ws + gpart_off, t);
    cell_kernel<<<128, 256, 0, stream>>>(ws + gpart_off, ws + biasg_off,
                                         ws + h_off, ws + c_off);
  }
  cls_kernel<<<64, 256, 0, stream>>>(ws + h_off, Wcls, bcls, out);
}

// Round 2
// 4797.116 us; speedup vs baseline: 1.6021x; 1.6021x over previous
//
#include <hip/hip_runtime.h>
#include <hip/hip_bf16.h>

// B=64, S=512, T=64, E=H=512, V=128, G=4H=2048, Kgates=512(ctx)+512(h)+128(tgt)=1152
// Strategy: precompute K2T=[b][e][s] (Wq folded into K), V, Wcomb (Wo folded into
// W_ih), then ONE persistent kernel runs all 64 recurrent steps with software
// grid barriers (256 blocks, guaranteed co-resident at 2 blocks/CU).

#define DI __device__ __forceinline__
typedef __hip_bfloat16 bf16;
typedef __hip_bfloat162 bf162;

DI float2 bf2f2(unsigned int u) {
  bf162 b = *reinterpret_cast<const bf162*>(&u);
  return __bfloat1622float2(b);
}
DI float sigm(float x) { return 1.f / (1.f + expf(-x)); }

// ---------------------------------------------------------------------------
// Generic 64x64-tile fp32 GEMM: C[m,n] = sum_k A[m,k] * B'[k,n] (+bias[n])
// BT: B is (N x K) row-major (A·Bt). OBF: store bf16. CT: store transposed
// within each 512-row batch block: C[b][n][s] (for K2T layout [b][e][s]).
// ---------------------------------------------------------------------------
template<bool BT, bool OBF, bool CT>
__launch_bounds__(256)
__global__ void gemm64(const float* __restrict__ A, const float* __restrict__ Bm,
                       void* __restrict__ Cp, const float* __restrict__ bias,
                       int M, int N, int K, int lda, int ldb, int ldc) {
  __shared__ __align__(16) float As[16][68];
  __shared__ __align__(16) float Bs[16][68];
  const int tid = threadIdx.x;
  const int n0 = blockIdx.x * 64;
  const int m0 = blockIdx.y * 64;
  const int tx = tid & 15, ty = tid >> 4;
  const int arow = tid >> 2;
  const int acol = (tid & 3) * 4;
  float acc[4][4] = {};
  for (int k0 = 0; k0 < K; k0 += 16) {
    float4 a4 = *(const float4*)&A[(size_t)(m0 + arow) * lda + k0 + acol];
    As[acol + 0][arow] = a4.x; As[acol + 1][arow] = a4.y;
    As[acol + 2][arow] = a4.z; As[acol + 3][arow] = a4.w;
    if (BT) {
      float4 b4 = *(const float4*)&Bm[(size_t)(n0 + arow) * ldb + k0 + acol];
      Bs[acol + 0][arow] = b4.x; Bs[acol + 1][arow] = b4.y;
      Bs[acol + 2][arow] = b4.z; Bs[acol + 3][arow] = b4.w;
    } else {
      const int brow = tid >> 4;
      const int bcol = (tid & 15) * 4;
      float4 b4 = *(const float4*)&Bm[(size_t)(k0 + brow) * ldb + n0 + bcol];
      *(float4*)&Bs[brow][bcol] = b4;
    }
    __syncthreads();
#pragma unroll
    for (int kk = 0; kk < 16; kk++) {
      float4 av = *(const float4*)&As[kk][ty * 4];
      float4 bv = *(const float4*)&Bs[kk][tx * 4];
      float a_[4] = {av.x, av.y, av.z, av.w};
      float b_[4] = {bv.x, bv.y, bv.z, bv.w};
#pragma unroll
      for (int i = 0; i < 4; i++)
#pragma unroll
        for (int j = 0; j < 4; j++) acc[i][j] += a_[i] * b_[j];
    }
    __syncthreads();
  }
#pragma unroll
  for (int i = 0; i < 4; i++) {
    const int m = m0 + ty * 4 + i;
#pragma unroll
    for (int j = 0; j < 4; j++) {
      const int n = n0 + tx * 4 + j;
      float v = acc[i][j] + (bias ? bias[n] : 0.f);
      if (OBF) {
        if (CT) {
          int bb = m >> 9, sE = m & 511;   // transposed within batch block
          ((bf16*)Cp)[((size_t)bb << 18) + (size_t)n * 512 + sE] = __float2bfloat16(v);
        } else {
          ((bf16*)Cp)[(size_t)m * ldc + n] = __float2bfloat16(v);
        }
      } else {
        ((float*)Cp)[(size_t)m * ldc + n] = v;
      }
    }
  }
}

// ---------------------------------------------------------------------------
// Small precompute kernels (unchanged from R1)
// ---------------------------------------------------------------------------
__launch_bounds__(256)
__global__ void transpose512(const float* __restrict__ src, float* __restrict__ dst) {
  int idx = blockIdx.x * 256 + threadIdx.x;
  int r = idx >> 9, c = idx & 511;
  dst[(size_t)c * 512 + r] = src[idx];
}

__launch_bounds__(256)
__global__ void colvec_kernel(const float* __restrict__ bvec, const float* __restrict__ W,
                              float* __restrict__ outv) {
  int e = blockIdx.x * 256 + threadIdx.x;
  float acc = 0.f;
  for (int f = 0; f < 512; f++) acc += bvec[f] * W[(size_t)f * 512 + e];
  outv[e] = acc;
}

__launch_bounds__(256)
__global__ void dot_kernel(const float* __restrict__ a, const float* __restrict__ b,
                           float* __restrict__ outp) {
  __shared__ float red[256];
  int tid = threadIdx.x;
  red[tid] = a[tid] * b[tid] + a[tid + 256] * b[tid + 256];
  __syncthreads();
  for (int st = 128; st > 0; st >>= 1) {
    if (tid < st) red[tid] += red[tid + st];
    __syncthreads();
  }
  if (tid == 0) *outp = red[0];
}

__launch_bounds__(256)
__global__ void svec_kernel(const float* __restrict__ mem, const float* __restrict__ wb,
                            const float* __restrict__ dotc, float* __restrict__ svec) {
  __shared__ __align__(16) float ws_[512];
  int tid = threadIdx.x;
  *(float2*)&ws_[tid * 2] = *(const float2*)&wb[tid * 2];
  __syncthreads();
  int bs = blockIdx.x * 256 + tid;
  const float4* mr = (const float4*)&mem[(size_t)bs * 512];
  const float4* w4 = (const float4*)ws_;
  float acc = *dotc;
#pragma unroll 4
  for (int j = 0; j < 128; j++) {
    float4 m = mr[j], w = w4[j];
    acc += m.x * w.x + m.y * w.y + m.z * w.z + m.w * w.w;
  }
  svec[bs] = acc;
}

__launch_bounds__(256)
__global__ void biasg_kernel(const float* __restrict__ W_ih, const float* __restrict__ b_ih,
                             const float* __restrict__ b_hh, const float* __restrict__ bo,
                             float* __restrict__ biasg) {
  int j = blockIdx.x * 256 + threadIdx.x;
  float acc = b_ih[j] + b_hh[j];
  const float4* wr = (const float4*)&W_ih[(size_t)j * 640];
  const float4* br = (const float4*)bo;
#pragma unroll 4
  for (int f4 = 0; f4 < 128; f4++) {
    float4 w = wr[f4], bb = br[f4];
    acc += w.x * bb.x + w.y * bb.y + w.z * bb.z + w.w * bb.w;
  }
  biasg[j] = acc;
}

__launch_bounds__(256)
__global__ void wcomb_copy(const float* __restrict__ W_hh, const float* __restrict__ W_ih,
                           float* __restrict__ Wcomb) {
  int idx = blockIdx.x * 256 + threadIdx.x;
  int j = idx / 640, cc = idx % 640;
  float v = (cc < 512) ? W_hh[(size_t)j * 512 + cc] : W_ih[(size_t)j * 640 + cc];
  Wcomb[(size_t)j * 1152 + 512 + cc] = v;
}

// ---------------------------------------------------------------------------
// Persistent step-loop kernel: 256 blocks, software grid barriers.
// ---------------------------------------------------------------------------
struct SMemA { float hs[512]; float buf[2048]; float p[128]; float red[2]; };
struct SMemB { float As[144][68]; float Bs[144][68]; };   // 78336 B
union SMemU { SMemA a; SMemB b; };

DI void gbar(unsigned* flags, unsigned* go, int slot) {
  const unsigned tgt = (unsigned)slot + 1u;
  __syncthreads();
  if (threadIdx.x == 0) {
    __threadfence();   // release: L2 writeback (cross-XCD visibility)
    __hip_atomic_store(&flags[blockIdx.x], tgt, __ATOMIC_RELAXED, __HIP_MEMORY_SCOPE_AGENT);
  }
  if (blockIdx.x == 0) {
    // 256 threads poll 256 flags in parallel
    while (__hip_atomic_load(&flags[threadIdx.x], __ATOMIC_RELAXED, __HIP_MEMORY_SCOPE_AGENT) < tgt)
      __builtin_amdgcn_s_sleep(2);
    __syncthreads();
    if (threadIdx.x == 0) {
      __threadfence();
      __hip_atomic_store(go, tgt, __ATOMIC_RELAXED, __HIP_MEMORY_SCOPE_AGENT);
    }
  }
  if (threadIdx.x == 0) {
    while (__hip_atomic_load(go, __ATOMIC_RELAXED, __HIP_MEMORY_SCOPE_AGENT) < tgt)
      __builtin_amdgcn_s_sleep(2);
    __threadfence();   // acquire: invalidate L1/L2
  }
  __syncthreads();
}

__launch_bounds__(256, 2)
__global__ void step_loop(const bf16* __restrict__ K2T, const bf16* __restrict__ Vv,
                          const float* __restrict__ svec, const float* __restrict__ Wcomb,
                          const float* __restrict__ biasg, const float* __restrict__ tgt,
                          const float* __restrict__ Wcls, const float* __restrict__ bcls,
                          float* __restrict__ h, float* __restrict__ c,
                          float* __restrict__ ctx, float* __restrict__ mlval,
                          unsigned* __restrict__ mlcnt, unsigned* flags, unsigned* go,
                          float* __restrict__ gpart, float* __restrict__ out) {
  __shared__ SMemU sm;
  const int blk = blockIdx.x, tid = threadIdx.x;
  const int b = blk >> 2, jj = blk & 3, s0 = jj * 128;
  const float SCALE = 0.04419417382415922f;  // 1/sqrt(512)
  int slot = 0;

  for (int t = 0; t <= 64; t++) {
    // ---- load h into LDS (fresh after barrier; zeroed at t=0 by memset) ----
    float2 h2 = *(const float2*)&h[(size_t)b * 512 + 2 * tid];
    *(float2*)&sm.a.hs[2 * tid] = h2;
    __syncthreads();

    // ---- classifier: out[t-1] = h_t @ Wcls^T + bcls (this block: 32 v's) ----
    if (t > 0) {
      int vl = tid >> 3, part = tid & 7;
      int v = jj * 32 + vl;
      const float4* wr = (const float4*)&Wcls[(size_t)v * 512 + part * 64];
      const float4* hr = (const float4*)&sm.a.hs[part * 64];
      float a = 0.f;
#pragma unroll
      for (int q = 0; q < 16; q++) {
        float4 w = wr[q], hh = hr[q];
        a += w.x * hh.x + w.y * hh.y + w.z * hh.z + w.w * hh.w;
      }
      a += __shfl_xor(a, 1); a += __shfl_xor(a, 2); a += __shfl_xor(a, 4);
      if (part == 0) out[((size_t)b * 64 + (t - 1)) * 128 + v] = a + bcls[v];
    }
    if (t == 64) return;

    // =========== PHASE A: attention (4 blocks per b, s-chunk of 128) ========
    // zero our ctx quarter (ordered before mlcnt release below)
    if (tid < 128)
      __hip_atomic_store(&ctx[(size_t)b * 512 + jj * 128 + tid], 0.f,
                         __ATOMIC_RELAXED, __HIP_MEMORY_SCOPE_AGENT);

    // scores: thread (eo=tid>>4, so=tid&15) -> 8 s-elems, partial over 32 e's
    {
      const int eo = tid >> 4, so = tid & 15;
      float a8[8] = {};
      const uint4* kp = (const uint4*)&K2T[((size_t)b << 18) + ((size_t)eo * 32) * 512 + s0 + 8 * so];
#pragma unroll 8
      for (int i = 0; i < 32; i++) {
        uint4 q = kp[(size_t)i * 64];
        float he = sm.a.hs[eo * 32 + i];
        float2 p0 = bf2f2(q.x), p1 = bf2f2(q.y), p2 = bf2f2(q.z), p3 = bf2f2(q.w);
        a8[0] += he * p0.x; a8[1] += he * p0.y; a8[2] += he * p1.x; a8[3] += he * p1.y;
        a8[4] += he * p2.x; a8[5] += he * p2.y; a8[6] += he * p3.x; a8[7] += he * p3.y;
      }
#pragma unroll
      for (int y = 0; y < 8; y++) sm.a.buf[eo * 128 + so * 8 + y] = a8[y];
    }
    __syncthreads();
    float pv = 0.f;
    if (tid < 128) {
      float sv = 0.f;
#pragma unroll
      for (int eo = 0; eo < 16; eo++) sv += sm.a.buf[eo * 128 + tid];
      pv = (sv + svec[(size_t)b * 512 + s0 + tid]) * SCALE;
      sm.a.p[tid] = pv;
    }
    __syncthreads();
    // local max
    if (tid < 64) {
      float v = fmaxf(sm.a.p[tid], sm.a.p[tid + 64]);
      for (int off = 32; off; off >>= 1) v = fmaxf(v, __shfl_down(v, off));
      if (tid == 0) sm.a.red[0] = v;
    }
    __syncthreads();
    const float mloc = sm.a.red[0];
    if (tid < 128) sm.a.p[tid] = __expf(pv - mloc);
    __syncthreads();
    if (tid < 64) {
      float v = sm.a.p[tid] + sm.a.p[tid + 64];
      for (int off = 32; off; off >>= 1) v += __shfl_down(v, off);
      if (tid == 0) sm.a.red[1] = v;
    }
    __syncthreads();
    const float lloc = sm.a.red[1];
    if (tid == 0) {
      __hip_atomic_store(&mlval[(b * 4 + jj) * 2 + 0], mloc, __ATOMIC_RELAXED, __HIP_MEMORY_SCOPE_AGENT);
      __hip_atomic_store(&mlval[(b * 4 + jj) * 2 + 1], lloc, __ATOMIC_RELAXED, __HIP_MEMORY_SCOPE_AGENT);
      __hip_atomic_fetch_add(&mlcnt[b], 1u, __ATOMIC_RELEASE, __HIP_MEMORY_SCOPE_AGENT);
    }
    // ctx partial: wave w covers s = 4i+w; lane l owns 8 e's (8l..8l+7)
    {
      const int w = tid >> 6, l = tid & 63;
      float c8[8] = {};
      const uint4* vp = (const uint4*)&Vv[((size_t)b << 18) + (size_t)s0 * 512 + 8 * l];
#pragma unroll 8
      for (int i = 0; i < 32; i++) {
        const int s = i * 4 + w;
        float ps = sm.a.p[s];
        uint4 q = vp[(size_t)s * 64];
        float2 p0 = bf2f2(q.x), p1 = bf2f2(q.y), p2 = bf2f2(q.z), p3 = bf2f2(q.w);
        c8[0] += ps * p0.x; c8[1] += ps * p0.y; c8[2] += ps * p1.x; c8[3] += ps * p1.y;
        c8[4] += ps * p2.x; c8[5] += ps * p2.y; c8[6] += ps * p3.x; c8[7] += ps * p3.y;
      }
#pragma unroll
      for (int y = 0; y < 8; y++) sm.a.buf[w * 512 + 8 * l + y] = c8[y];
    }
    // wait for all 4 sibling (m,l) posts of this b
    if (tid == 0) {
      while (__hip_atomic_load(&mlcnt[b], __ATOMIC_RELAXED, __HIP_MEMORY_SCOPE_AGENT) < 4u * (t + 1))
        __builtin_amdgcn_s_sleep(1);
    }
    __syncthreads();
    {
      float mj[4], lj[4], M = -1e30f;
#pragma unroll
      for (int q2 = 0; q2 < 4; q2++) {
        mj[q2] = __hip_atomic_load(&mlval[(b * 4 + q2) * 2 + 0], __ATOMIC_RELAXED, __HIP_MEMORY_SCOPE_AGENT);
        lj[q2] = __hip_atomic_load(&mlval[(b * 4 + q2) * 2 + 1], __ATOMIC_RELAXED, __HIP_MEMORY_SCOPE_AGENT);
        M = fmaxf(M, mj[q2]);
      }
      float L = 0.f;
#pragma unroll
      for (int q2 = 0; q2 < 4; q2++) L += __expf(mj[q2] - M) * lj[q2];
      const float msc = __expf(mj[jj] - M) / L;
      const int e = 2 * tid;
      float cx = sm.a.buf[0 * 512 + e] + sm.a.buf[1 * 512 + e] + sm.a.buf[2 * 512 + e] + sm.a.buf[3 * 512 + e];
      float cy = sm.a.buf[0 * 512 + e + 1] + sm.a.buf[1 * 512 + e + 1] + sm.a.buf[2 * 512 + e + 1] + sm.a.buf[3 * 512 + e + 1];
      atomicAdd(&ctx[(size_t)b * 512 + e], cx * msc);
      atomicAdd(&ctx[(size_t)b * 512 + e + 1], cy * msc);
    }
    gbar(flags, go, slot++);

    // ======= PHASE B: gates GEMM, 64x64x144 tile (32 n-chunks x 8 k-chunks) ==
    {
      const int ks = blk >> 5;
      const int n0 = (blk & 31) * 64;
      const int k0 = ks * 144;
      for (int q = tid; q < 2304; q += 256) {
        int m = q / 36, c4 = (q % 36) * 4;
        int k = k0 + c4;
        float4 xv;
        if (k < 512)       xv = *(const float4*)&ctx[(size_t)m * 512 + k];
        else if (k < 1024) xv = *(const float4*)&h[(size_t)m * 512 + (k - 512)];
        else               xv = *(const float4*)&tgt[((size_t)m * 64 + t) * 128 + (k - 1024)];
        sm.b.As[c4 + 0][m] = xv.x; sm.b.As[c4 + 1][m] = xv.y;
        sm.b.As[c4 + 2][m] = xv.z; sm.b.As[c4 + 3][m] = xv.w;
        float4 wv = *(const float4*)&Wcomb[(size_t)(n0 + m) * 1152 + k];
        sm.b.Bs[c4 + 0][m] = wv.x; sm.b.Bs[c4 + 1][m] = wv.y;
        sm.b.Bs[c4 + 2][m] = wv.z; sm.b.Bs[c4 + 3][m] = wv.w;
      }
      __syncthreads();
      const int tx = tid & 15, ty = tid >> 4;
      float acc[4][4] = {};
#pragma unroll 4
      for (int kk = 0; kk < 144; kk++) {
        float4 av = *(const float4*)&sm.b.As[kk][ty * 4];
        float4 bv = *(const float4*)&sm.b.Bs[kk][tx * 4];
        float a_[4] = {av.x, av.y, av.z, av.w};
        float b_[4] = {bv.x, bv.y, bv.z, bv.w};
#pragma unroll
        for (int i = 0; i < 4; i++)
#pragma unroll
          for (int j2 = 0; j2 < 4; j2++) acc[i][j2] += a_[i] * b_[j2];
      }
#pragma unroll
      for (int i = 0; i < 4; i++)
#pragma unroll
        for (int j2 = 0; j2 < 4; j2++)
          gpart[(size_t)ks * 131072 + (size_t)(ty * 4 + i) * 2048 + n0 + tx * 4 + j2] = acc[i][j2];
    }
    gbar(flags, go, slot++);

    // ============== PHASE C: split-K reduce + LSTM cell (128 blocks) ========
    if (blk < 128) {
      const int idx = blk * 256 + tid;       // 0..32767
      const int bb = idx >> 9, d = idx & 511;
      float g0 = 0.f, g1 = 0.f, g2 = 0.f, g3 = 0.f;
#pragma unroll
      for (int q2 = 0; q2 < 8; q2++) {
        const float* gp = gpart + (size_t)q2 * 131072 + (size_t)bb * 2048;
        g0 += gp[d]; g1 += gp[512 + d]; g2 += gp[1024 + d]; g3 += gp[1536 + d];
      }
      g0 += biasg[d]; g1 += biasg[512 + d]; g2 += biasg[1024 + d]; g3 += biasg[1536 + d];
      float cold = c[idx];
      float cn = sigm(g1) * cold + sigm(g0) * tanhf(g2);
      float hn = sigm(g3) * tanhf(cn);
      __hip_atomic_store(&c[idx], cn, __ATOMIC_RELAXED, __HIP_MEMORY_SCOPE_AGENT);
      __hip_atomic_store(&h[idx], hn, __ATOMIC_RELAXED, __HIP_MEMORY_SCOPE_AGENT);
    }
    gbar(flags, go, slot++);
  }
}

// ---------------------------------------------------------------------------
extern "C" void kernel_launch(void* const* d_in, const int* in_sizes, int n_in,
                              void* d_out, int out_size, void* d_ws, size_t ws_size,
                              hipStream_t stream) {
  const float* memory = (const float*)d_in[0];
  const float* tgt    = (const float*)d_in[1];
  const float* Wq     = (const float*)d_in[2];
  const float* bq     = (const float*)d_in[3];
  const float* Wk     = (const float*)d_in[4];
  const float* bk     = (const float*)d_in[5];
  const float* Wv     = (const float*)d_in[6];
  const float* bv     = (const float*)d_in[7];
  const float* Wo     = (const float*)d_in[8];
  const float* bo     = (const float*)d_in[9];
  const float* W_ih   = (const float*)d_in[10];
  const float* b_ih   = (const float*)d_in[11];
  const float* W_hh   = (const float*)d_in[12];
  const float* b_hh   = (const float*)d_in[13];
  const float* Wcls   = (const float*)d_in[14];
  const float* bcls   = (const float*)d_in[15];
  float* out = (float*)d_out;

  float* ws = (float*)d_ws;
  size_t off = 0;
  auto alloc = [&](size_t n) { size_t r = off; off += (n + 15) & ~(size_t)15; return r; };
  const size_t K2_off    = alloc(8388608);   // bf16 x 16777216: K2T [b][e][s]
  const size_t V_off     = alloc(8388608);   // bf16 x 16777216: V  [b][s][e]
  const size_t Wcomb_off = alloc(2359296);   // 2048 x 1152
  const size_t Wkq_off   = alloc(262144);
  const size_t WkT_off   = alloc(262144);
  const size_t svec_off  = alloc(32768);
  const size_t sb_off    = alloc(512);
  const size_t wb_off    = alloc(512);
  const size_t dotc_off  = alloc(16);
  const size_t biasg_off = alloc(2048);
  const size_t h_off     = alloc(32768);
  const size_t c_off     = alloc(32768);     // contiguous with h
  const size_t sync_off  = alloc(512);       // flags[256], go@272, mlcnt@384 (uints)
  const size_t ctx_off   = alloc(32768);
  const size_t mlval_off = alloc(512);
  const size_t gpart_off = alloc(1048576);   // 8 x 64 x 2048

  bf16* K2T = (bf16*)(ws + K2_off);
  bf16* Vv  = (bf16*)(ws + V_off);
  unsigned* flags = (unsigned*)(ws + sync_off);
  unsigned* go    = flags + 272;
  unsigned* mlcnt = flags + 384;

  // zero h, c, and sync area in one shot (adjacent allocs)
  hipMemsetAsync(ws + h_off, 0, (32768 + 32768 + 512) * sizeof(float), stream);

  // ---- precompute (step-invariant) ----
  transpose512<<<1024, 256, 0, stream>>>(Wk, ws + WkT_off);
  colvec_kernel<<<2, 256, 0, stream>>>(bk, Wq, ws + sb_off);
  colvec_kernel<<<2, 256, 0, stream>>>(bq, Wk, ws + wb_off);
  dot_kernel<<<1, 256, 0, stream>>>(bq, bk, ws + dotc_off);
  gemm64<false, false, false><<<dim3(8, 8), 256, 0, stream>>>(
      ws + WkT_off, Wq, ws + Wkq_off, nullptr, 512, 512, 512, 512, 512, 512);
  // K2T[b][e][s] = (memory @ Wkq + sb) transposed per batch (bf16)
  gemm64<false, true, true><<<dim3(8, 512), 256, 0, stream>>>(
      memory, ws + Wkq_off, K2T, ws + sb_off, 32768, 512, 512, 512, 512, 512);
  // V[b][s][e] = memory @ Wv^T + bv (bf16)
  gemm64<true, true, false><<<dim3(8, 512), 256, 0, stream>>>(
      memory, Wv, Vv, bv, 32768, 512, 512, 512, 512, 512);
  gemm64<false, false, false><<<dim3(8, 32), 256, 0, stream>>>(
      W_ih, Wo, ws + Wcomb_off, nullptr, 2048, 512, 512, 640, 512, 1152);
  wcomb_copy<<<5120, 256, 0, stream>>>(W_hh, W_ih, ws + Wcomb_off);
  biasg_kernel<<<8, 256, 0, stream>>>(W_ih, b_ih, b_hh, bo, ws + biasg_off);
  svec_kernel<<<128, 256, 0, stream>>>(memory, ws + wb_off, ws + dotc_off, ws + svec_off);

  // ---- all 64 recurrent steps in one persistent kernel ----
  step_loop<<<256, 256, 0, stream>>>(K2T, Vv, ws + svec_off, ws + Wcomb_off,
                                     ws + biasg_off, tgt, Wcls, bcls,
                                     ws + h_off, ws + c_off, ws + ctx_off,
                                     ws + mlval_off, mlcnt, flags, go,
                                     ws + gpart_off, out);
}